// Round 13
// baseline (53.174 us; speedup 1.0000x reference)
//
#include <hip/hip_runtime.h>

#define EPSF 1e-7f

typedef unsigned int u32;

// ---- DPP cross-lane helpers (VALU pipe, no DS; verified R2-R12) ----
#define DPPF0(x, ctrl) \
    __int_as_float(__builtin_amdgcn_update_dpp(0, __float_as_int(x), ctrl, 0xF, 0xF, false))

__device__ __forceinline__ float f_rcp(float x) { return __builtin_amdgcn_rcpf(x); }
__device__ __forceinline__ float wave_shr1_f(float x) { return DPPF0(x, 0x138); }

__device__ __forceinline__ float wave_max64(float x) {
    x = fmaxf(x, DPPF0(x, 0x111));   // row_shr:1
    x = fmaxf(x, DPPF0(x, 0x112));   // row_shr:2
    x = fmaxf(x, DPPF0(x, 0x114));   // row_shr:4
    x = fmaxf(x, DPPF0(x, 0x118));   // row_shr:8
    x = fmaxf(x, DPPF0(x, 0x142));   // row_bcast:15
    x = fmaxf(x, DPPF0(x, 0x143));   // row_bcast:31
    return __int_as_float(__builtin_amdgcn_readlane(__float_as_int(x), 63));
}

__device__ __forceinline__ float wave_sum64(float x) {
    x += DPPF0(x, 0x111);
    x += DPPF0(x, 0x112);
    x += DPPF0(x, 0x114);
    x += DPPF0(x, 0x118);
    x += DPPF0(x, 0x142);
    x += DPPF0(x, 0x143);
    return __int_as_float(__builtin_amdgcn_readlane(__float_as_int(x), 63));
}

// pack two fp32 -> bf16x2 word (RNE); unpack is shift/and (1 VALU each)
__device__ __forceinline__ u32 pack_bf2(float a, float b) {
    u32 ua = __float_as_uint(a), ub = __float_as_uint(b);
    ua += 0x7FFFu + ((ua >> 16) & 1u);
    ub += 0x7FFFu + ((ub >> 16) & 1u);
    return (ua >> 16) | (ub & 0xFFFF0000u);
}

// ---- one CTC step, q-normalized (R4/R12-verified math), bf16 q pair ----
#define STEPQ(PW_) do { \
    const u32 w_ = (PW_); \
    const float q1 = __uint_as_float(w_ << 16); \
    const float q3 = __uint_as_float(w_ & 0xFFFF0000u); \
    const float n3 = wave_shr1_f(u3); \
    const float t1 = fmaf(m1, n3, u0 + u1); \
    const float t3 = fmaf(m3, u1, u2 + u3); \
    u4 = u4 + u3; \
    u3 = t3 * q3; \
    u2 = u2 + u1; \
    u1 = t1 * q1; \
    u0 = u0 + n3; \
} while (0)

#define SNAP2(RM, LM) do { \
    float mm_ = fmaxf(fmaxf(u0, u1), fmaxf(u2, fmaxf(u3, u4))); \
    mm_ = wave_max64(mm_); \
    RM = f_rcp(mm_); \
    LM = __logf(mm_); \
} while (0)

#define APPLY2(RM, LM) do { \
    u0 *= RM; u1 *= RM; u2 *= RM; u3 *= RM; u4 *= RM; \
    O += LM; \
} while (0)

// load one 8-row window of q-words from LDS (lane-linear, conflict-free)
#define LDW(X, BASE) do { \
    X##0 = qkl[(BASE) + 0][lane]; X##1 = qkl[(BASE) + 1][lane]; \
    X##2 = qkl[(BASE) + 2][lane]; X##3 = qkl[(BASE) + 3][lane]; \
    X##4 = qkl[(BASE) + 4][lane]; X##5 = qkl[(BASE) + 5][lane]; \
    X##6 = qkl[(BASE) + 6][lane]; X##7 = qkl[(BASE) + 7][lane]; \
} while (0)

// full window, R4 cadence: apply@2 (prev snap), snap@4, apply@6, snap@8
#define CONS8W(X) do { \
    STEPQ(X##0); STEPQ(X##1); APPLY2(rmA, lmA); \
    STEPQ(X##2); STEPQ(X##3); SNAP2(rmB, lmB); \
    STEPQ(X##4); STEPQ(X##5); APPLY2(rmB, lmB); \
    STEPQ(X##6); STEPQ(X##7); SNAP2(rmA, lmA); \
} while (0)

// window 0: rows 1..7 (row 0 is the init), same bounded cadence
#define CONS0W(X) do { \
    STEPQ(X##1); STEPQ(X##2); APPLY2(rmA, lmA); \
    STEPQ(X##3); STEPQ(X##4); SNAP2(rmB, lmB); \
    STEPQ(X##5); STEPQ(X##6); APPLY2(rmB, lmB); \
    STEPQ(X##7); SNAP2(rmA, lmA); \
} while (0)

// =====================================================================
// Fused kernel v2, T=512/C=128/U=128. One block (4 waves) per batch row.
// Phase 1: stream y_pred through a 32-row LDS stage (coalesced float4
//   register loads, next chunk issued before current gather), LDS-gather
//   label+blank probs, precompute q=(p+eps)/(pb+eps), store bf16x2 in
//   qkl[512][64]; blank column -> pbl[512]. ZERO scattered TA gathers.
// Phase 2 (wave 0): 511-step scan; 8 conflict-free ds_reads per window;
//   per step: 2 bit-ops + 9 VALU + 1 DPP. No rcp/log on the step path.
// =====================================================================
__global__ __launch_bounds__(256, 1) void ctc_fused512b(
        const int* __restrict__ y_true, const float* __restrict__ y_pred,
        float* __restrict__ out) {
    __shared__ u32   qkl[512][64];     // 128 KB: bf16x2(q1,q3) per (t,lane)
    __shared__ float pbl[512];         // 2 KB: blank prob per row
    __shared__ float stage[32][128];   // 16 KB: one 32-row chunk of y_pred

    const int b    = blockIdx.x;
    const int tid  = threadIdx.x;
    const int w    = tid >> 6;
    const int lane = tid & 63;
    const float* __restrict__ yp = y_pred + (size_t)b * (512 * 128);

    const int2 lc = ((const int2*)(y_true + (size_t)b * 128))[lane];
    const int c1 = lc.x, c3 = lc.y;

    // staging assignment: thread covers float4 slots tid, tid+256, tid+512, tid+768
    // slot f -> row f>>5, col (f&31)*4  (32 rows x 128 floats = 1024 float4)
    float4 rg[4];
    {   // prologue: load chunk 0 into regs, write to stage
        const float* src = yp;
#pragma unroll
        for (int i = 0; i < 4; ++i) {
            const int f = tid + i * 256;
            rg[i] = *(const float4*)(src + (size_t)(f >> 5) * 128 + ((f & 31) << 2));
        }
#pragma unroll
        for (int i = 0; i < 4; ++i) {
            const int f = tid + i * 256;
            *(float4*)(&stage[f >> 5][(f & 31) << 2]) = rg[i];
        }
    }
    __syncthreads();

    // 16 chunks of 32 rows
    for (int k = 0; k < 16; ++k) {
        // issue next chunk's loads early (latency hides under gather)
        if (k < 15) {
            const float* src = yp + (size_t)(k + 1) * 32 * 128;
#pragma unroll
            for (int i = 0; i < 4; ++i) {
                const int f = tid + i * 256;
                rg[i] = *(const float4*)(src + (size_t)(f >> 5) * 128 + ((f & 31) << 2));
            }
        }
        // gather chunk k: wave w handles rows w*8 .. w*8+7
        {
            const int cb = k * 32;
#pragma unroll
            for (int rr = 0; rr < 8; ++rr) {
                const int r = w * 8 + rr;
                const float pv1 = stage[r][c1];
                const float pv3 = stage[r][c3];
                const float pvb = stage[r][127];
                const float rpb = f_rcp(pvb + EPSF);
                const float q1  = (pv1 + EPSF) * rpb;
                const float q3  = (pv3 + EPSF) * rpb;
                qkl[cb + r][lane] = pack_bf2(q1, q3);
            }
            if (tid < 32) pbl[cb + tid] = stage[tid][127];
        }
        __syncthreads();               // all gathers of chunk k done
        if (k < 15) {
#pragma unroll
            for (int i = 0; i < 4; ++i) {
                const int f = tid + i * 256;
                *(float4*)(&stage[f >> 5][(f & 31) << 2]) = rg[i];
            }
        }
        __syncthreads();               // stage holds chunk k+1
    }

    if (w != 0) return;

    // ---- phase 2: scan (wave 0 only) ----
    const int cp = __builtin_amdgcn_update_dpp(0, c3, 0x138, 0xF, 0xF, false);
    const float m1 = (lane > 0 && c1 != cp) ? 1.f : 0.f;
    const float m3 = (c3 != c1) ? 1.f : 0.f;

    // blank log-sum over rows 1..511 (scan-independent, wave-parallel)
    float bls = 0.f;
#pragma unroll
    for (int kk = 0; kk < 8; ++kk) {
        const int t = lane * 8 + kk;
        if (t >= 1) bls += __logf(pbl[t] + EPSF);
    }
    bls = wave_sum64(bls);

    // init from row 0 (exact fp32 from global)
    float u0, u1, u2 = 0.f, u3 = 0.f, u4 = 0.f;
    u0 = (lane == 0) ? yp[127] + EPSF : 0.f;
    u1 = (lane == 0) ? yp[c1] + EPSF : 0.f;
    float O = 0.f;
    float rmA = 1.0f, lmA = 0.0f, rmB = 1.0f, lmB = 0.0f;

    u32 A0, A1, A2, A3, A4, A5, A6, A7;
    u32 B0, B1, B2, B3, B4, B5, B6, B7;

    LDW(A, 0);                       // W0 (rows 0..7)
    LDW(B, 8);                       // W1 prefetch
    CONS0W(A);                       // steps: rows 1..7

    for (int j = 0; j < 31; ++j) {
        LDW(A, 16 * j + 16); CONS8W(B);   // consume W(2j+1), prefetch W(2j+2)
        LDW(B, 16 * j + 24); CONS8W(A);   // consume W(2j+2), prefetch W(2j+3)
    }
    CONS8W(B);                       // W63 (rows 504..511)

    if (lane == 63) out[b] = -(O + bls + __logf(u3 + u4));
}

// =====================================================================
// Generic fallback (other shapes), R12-verified.
// =====================================================================
__global__ __launch_bounds__(64, 1) void ctc_scan_generic(
        const int* __restrict__ y_true, const float* __restrict__ y_pred,
        float* __restrict__ out, int T, int C, int U) {
    const int b    = blockIdx.x;
    const int lane = threadIdx.x;
    const int blank = C - 1;
    const float* __restrict__ yp = y_pred + (size_t)b * T * C;

    const int2 lc = ((const int2*)(y_true + (size_t)b * U))[lane];
    const int c1 = lc.x, c3 = lc.y;
    const int cp = __builtin_amdgcn_update_dpp(0, c3, 0x138, 0xF, 0xF, false);
    const float m1 = (lane > 0 && c1 != cp) ? 1.f : 0.f;
    const float m3 = (c3 != c1) ? 1.f : 0.f;

    float u0, u1, u2 = 0.f, u3 = 0.f, u4 = 0.f;
    u0 = (lane == 0) ? yp[blank] + EPSF : 0.f;
    u1 = (lane == 0) ? yp[c1] + EPSF : 0.f;
    float O = 0.f;
    float rmA = 1.0f, lmA = 0.0f;
    int kren = 0;

    for (int t = 1; t < T; ++t) {
        const float* row = yp + (size_t)t * C;
        const float pbe = row[blank] + EPSF;
        const float rpb = f_rcp(pbe);
        const float q1  = (row[c1] + EPSF) * rpb;
        const float q3  = (row[c3] + EPSF) * rpb;
        const float n3  = wave_shr1_f(u3);
        const float t1  = fmaf(m1, n3, u0 + u1);
        const float t3  = fmaf(m3, u1, u2 + u3);
        u4 = u4 + u3;
        u3 = t3 * q3;
        u2 = u2 + u1;
        u1 = t1 * q1;
        u0 = u0 + n3;
        O += __logf(pbe);
        if (++kren == 4) { SNAP2(rmA, lmA); APPLY2(rmA, lmA); kren = 0; }
    }
    if (lane == 63) out[b] = -(O + __logf(u3 + u4));
}

extern "C" void kernel_launch(void* const* d_in, const int* in_sizes, int n_in,
                              void* d_out, int out_size, void* d_ws, size_t ws_size,
                              hipStream_t stream) {
    const int*   y_true = (const int*)d_in[0];
    const float* y_pred = (const float*)d_in[1];
    float*       out    = (float*)d_out;

    const int B = out_size;                 // 256
    const int U = in_sizes[0] / B;          // 128
    const int C = 128;                      // classes incl. blank
    const int T = in_sizes[1] / (B * C);    // 512

    if (T == 512 && C == 128 && U == 128) {
        ctc_fused512b<<<B, 256, 0, stream>>>(y_true, y_pred, out);
    } else {
        ctc_scan_generic<<<B, 64, 0, stream>>>(y_true, y_pred, out, T, C, U);
    }
}